// Round 6
// baseline (400.551 us; speedup 1.0000x reference)
//
#include <hip/hip_runtime.h>

// RGCN block: B=512, C=256, R=8, N=81 (9x9), fp32 in/out, bf16 MFMA compute.
// Transposed formulation: msgT[c][n] = h^T @ adj^T ; out^T[d][n] = W^T @ msg.
// Grid: 1024 blocks = (b, n-half of 48 rows). 8 waves, each 32 d x 48 n output.
// R6: double-buffered adj+msg in LDS -> ONE barrier per relation; adj prefetch
// aged one full iteration (no exposed vmcnt); wt prefetched 3 k-batches ahead.

#define B_SZ 512
#define C_SZ 256
#define R_SZ 8
#define N_SZ 81
#define TH 512

typedef short bf16x8 __attribute__((ext_vector_type(8)));
typedef float f32x4 __attribute__((ext_vector_type(4)));

__device__ __forceinline__ unsigned short f2bf(float f) {
    union { float f; unsigned u; } v; v.f = f;
    unsigned r = v.u + 0x7FFFu + ((v.u >> 16) & 1u);   // RNE
    return (unsigned short)(r >> 16);
}

// pack 4 f32 -> 4 bf16 in one u64, v[0] lowest address
__device__ __forceinline__ unsigned long long pack4bf(f32x4 v) {
    unsigned long long r;
    r  = (unsigned long long)f2bf(v[0]);
    r |= (unsigned long long)f2bf(v[1]) << 16;
    r |= (unsigned long long)f2bf(v[2]) << 32;
    r |= (unsigned long long)f2bf(v[3]) << 48;
    return r;
}

// LDS: adj buffers 2 x [48][88] bf16 ; msg buffers 2 x (48 rows x 512 B, swizzled)
#define ADJ_OFF  0                      // 2 * 8448 = 16896 B
#define MSG_OFF  16896                  // 2 * 24576 = 49152 B
#define SMEM_SZ  (16896 + 49152 + 32)   // 66080 B -> 2 blocks/CU

__device__ __forceinline__ int adj_base(int buf) { return ADJ_OFF + buf * 8448; }

__device__ __forceinline__ int msg_addr(int buf, int n, int cbyte) {
    int s = (n ^ (n >> 3)) & 7;
    return MSG_OFF + buf * 24576 + n * 512 + (cbyte ^ (s << 4));
}

// ---- kernel 0: weight (R,C,C) fp32 -> WT[r][d][c] bf16 ----
__global__ void prep_wt(const float* __restrict__ w, unsigned short* __restrict__ wt) {
    int i = blockIdx.x * blockDim.x + threadIdx.x;
    if (i >= R_SZ * C_SZ * C_SZ) return;
    int r = i >> 16;
    int d = (i >> 8) & 255;
    int c = i & 255;
    wt[i] = f2bf(w[(r * C_SZ + c) * C_SZ + d]);
}

// ---- kernel 1: fused RGCN, one block per (batch, n-half) ----
__launch_bounds__(TH, 4)
__global__ void rgcn_main(const float* __restrict__ x,
                          const float* __restrict__ adj,
                          const unsigned short* __restrict__ wt,
                          float* __restrict__ out,
                          float* __restrict__ psum) {
    __shared__ __align__(16) unsigned char smem[SMEM_SZ];

    // XCD co-location (1024 % 8 == 0 -> bijective)
    const int bid  = blockIdx.x;
    const int xcd  = bid & 7;
    const int slot = bid >> 3;            // 0..127
    const int b    = xcd * 64 + (slot >> 1);
    const int half = slot & 1;
    const int n0   = half * 48;
    const int nvalid = half ? 33 : 48;
    const int cnt  = nvalid * N_SZ;

    const int tid  = threadIdx.x;
    const int lane = tid & 63;
    const int wave = tid >> 6;            // 0..7
    const int lr   = lane & 15;
    const int lk   = lane >> 4;
    const int cb   = wave * 32;           // this wave's 32 c rows (stage1) / d rows (stage2)

    const float* xb   = x + (size_t)b * C_SZ * N_SZ;
    const float* adjb = adj + ((size_t)b * R_SZ * N_SZ + n0) * N_SZ;

    // ---- h fragments in registers, relation-invariant (m>=81 zeroed) ----
    bf16x8 hfr[3][2];
#pragma unroll
    for (int kk = 0; kk < 3; ++kk) {
#pragma unroll
        for (int jc = 0; jc < 2; ++jc) {
            int c = cb + jc * 16 + lr;
            const float* src = xb + c * N_SZ;
#pragma unroll
            for (int e = 0; e < 8; ++e) {
                int m = kk * 32 + lk * 8 + e;
                hfr[kk][jc][e] = (m < N_SZ) ? (short)f2bf(src[m]) : (short)0;
            }
        }
    }

    // ---- zero both adj buffers (pads m>=81, rows n>=nvalid stay zero) ----
    for (int i = tid; i < 16896 / 4; i += TH) ((unsigned*)smem)[i] = 0;

    // ---- adj(0): load + write buf0; then issue adj(1) prefetch ----
    float pf[8];
#pragma unroll
    for (int u = 0; u < 8; ++u) {
        int i2 = tid + u * TH;
        pf[u] = (i2 < cnt) ? adjb[i2] : 0.f;
    }
    __syncthreads();   // zero-init complete before value stores
    {
        unsigned short* a0 = (unsigned short*)(smem + adj_base(0));
#pragma unroll
        for (int u = 0; u < 8; ++u) {
            int i2 = tid + u * TH;
            if (i2 < cnt) {
                int n = i2 / N_SZ, m = i2 - n * N_SZ;
                a0[n * 88 + m] = f2bf(pf[u]);
            }
        }
    }
    // prefetch adj(1) (consumed next iteration's write -> fully aged)
#pragma unroll
    for (int u = 0; u < 8; ++u) {
        int i2 = tid + u * TH;
        pf[u] = (i2 < cnt) ? adjb[1 * (N_SZ * N_SZ) + i2] : 0.f;
    }
    __syncthreads();   // adj(0) ready

    const f32x4 vzero = {0.f, 0.f, 0.f, 0.f};
    f32x4 acc[2][3];
#pragma unroll
    for (int jd = 0; jd < 2; ++jd)
#pragma unroll
        for (int jn = 0; jn < 3; ++jn) acc[jd][jn] = vzero;

#pragma unroll 1
    for (int r = 0; r < R_SZ; ++r) {
        const int cur = r & 1;
        const unsigned short* adjc = (const unsigned short*)(smem + adj_base(cur));
        const unsigned short* wr   = wt + r * (C_SZ * C_SZ);

        // ---- wt prefetch, 3 k-batches ahead (w[kk%4], statically unrolled) ----
        bf16x8 w0[2], w1[2], w2[2], w3[2];   // [jd], one kk each
#pragma unroll
        for (int jd = 0; jd < 2; ++jd) {
            const unsigned short* wrow = wr + (cb + jd * 16 + lr) * 256 + lk * 8;
            w0[jd] = *(const bf16x8*)&wrow[0 * 32];
            w1[jd] = *(const bf16x8*)&wrow[1 * 32];
            w2[jd] = *(const bf16x8*)&wrow[2 * 32];
        }

        // ---- stage 1: msgT[c][n] ; A=h (regs), B=adj (LDS, current buffer) ----
        f32x4 macc[2][3];
#pragma unroll
        for (int jc = 0; jc < 2; ++jc)
#pragma unroll
            for (int jn = 0; jn < 3; ++jn) macc[jc][jn] = vzero;

#pragma unroll
        for (int kk = 0; kk < 3; ++kk) {
            bf16x8 bfr[3];
#pragma unroll
            for (int jn = 0; jn < 3; ++jn)
                bfr[jn] = *(const bf16x8*)&adjc[(jn * 16 + lr) * 88 + kk * 32 + lk * 8];
#pragma unroll
            for (int jc = 0; jc < 2; ++jc)
#pragma unroll
                for (int jn = 0; jn < 3; ++jn)
                    macc[jc][jn] = __builtin_amdgcn_mfma_f32_16x16x32_bf16(hfr[kk][jc], bfr[jn], macc[jc][jn], 0, 0, 0);
        }

        // ---- write msg -> msgbuf[cur] (no barrier needed: prev readers synced) ----
#pragma unroll
        for (int jc = 0; jc < 2; ++jc) {
#pragma unroll
            for (int jn = 0; jn < 3; ++jn) {
                int n = jn * 16 + lr;
                int cbyte = (cb + jc * 16 + lk * 4) * 2;
                *(unsigned long long*)(smem + msg_addr(cur, n, cbyte)) = pack4bf(macc[jc][jn]);
            }
        }

        // ---- write aged adj(r+1) -> other buffer; then issue adj(r+2) ----
        if (r < R_SZ - 1) {
            unsigned short* an = (unsigned short*)(smem + adj_base(cur ^ 1));
#pragma unroll
            for (int u = 0; u < 8; ++u) {
                int i2 = tid + u * TH;
                if (i2 < cnt) {
                    int n = i2 / N_SZ, m = i2 - n * N_SZ;
                    an[n * 88 + m] = f2bf(pf[u]);
                }
            }
            if (r < R_SZ - 2) {
                const float* src = adjb + (r + 2) * (N_SZ * N_SZ);
#pragma unroll
                for (int u = 0; u < 8; ++u) {
                    int i2 = tid + u * TH;
                    pf[u] = (i2 < cnt) ? src[i2] : 0.f;
                }
            }
        }

        __syncthreads();   // the ONLY barrier: msg[cur] + adj[cur^1] ready

        // ---- stage 2: acc += W^T @ msg (K=256); w[] rotation 3 ahead ----
        bf16x8* wsets[4] = {w0, w1, w2, w3};
#pragma unroll
        for (int kk = 0; kk < 8; ++kk) {
            if (kk + 3 < 8) {
                bf16x8* wn = wsets[(kk + 3) & 3];
#pragma unroll
                for (int jd = 0; jd < 2; ++jd)
                    wn[jd] = *(const bf16x8*)&wr[(cb + jd * 16 + lr) * 256 + (kk + 3) * 32 + lk * 8];
            }
            bf16x8* wc = wsets[kk & 3];
            bf16x8 bfr[3];
#pragma unroll
            for (int jn = 0; jn < 3; ++jn)
                bfr[jn] = *(const bf16x8*)(smem + msg_addr(cur, jn * 16 + lr, kk * 64 + lk * 16));
#pragma unroll
            for (int jd = 0; jd < 2; ++jd)
#pragma unroll
                for (int jn = 0; jn < 3; ++jn)
                    acc[jd][jn] = __builtin_amdgcn_mfma_f32_16x16x32_bf16(wc[jd], bfr[jn], acc[jd][jn], 0, 0, 0);
        }
    }

    // ---- epilogue: pre = out^T + x ; n-contiguous stores ; BN partials ----
    float* outb = out + (size_t)b * C_SZ * N_SZ;
    const int bh = b * 2 + half;
#pragma unroll
    for (int jd = 0; jd < 2; ++jd) {
        float s1[4] = {0.f, 0.f, 0.f, 0.f};
        float s2[4] = {0.f, 0.f, 0.f, 0.f};
#pragma unroll
        for (int jn = 0; jn < 3; ++jn) {
            int nloc = jn * 16 + lr;
            bool ok = nloc < nvalid;
            int n = n0 + nloc;
#pragma unroll
            for (int q = 0; q < 4; ++q) {
                int d = cb + jd * 16 + lk * 4 + q;
                if (ok) {
                    float pre = acc[jd][jn][q] + xb[d * N_SZ + n];
                    outb[d * N_SZ + n] = pre;
                    s1[q] += pre;
                    s2[q] += pre * pre;
                }
            }
        }
#pragma unroll
        for (int q = 0; q < 4; ++q) {
#pragma unroll
            for (int msk = 8; msk > 0; msk >>= 1) {
                s1[q] += __shfl_xor(s1[q], msk);
                s2[q] += __shfl_xor(s2[q], msk);
            }
        }
        if (lr == 0) {
#pragma unroll
            for (int q = 0; q < 4; ++q) {
                int d = cb + jd * 16 + lk * 4 + q;
                psum[(size_t)d * 1024 + bh] = s1[q];
                psum[(size_t)C_SZ * 1024 + (size_t)d * 1024 + bh] = s2[q];
            }
        }
    }
}

// ---- kernel 2: reduce partials -> scale/shift per channel ----
__global__ void bn_stats(const float* __restrict__ psum,
                         const float* __restrict__ gamma, const float* __restrict__ beta,
                         float* __restrict__ mr) {
    int c = blockIdx.x;      // 256 blocks x 64 threads
    int t = threadIdx.x;
    float a = 0.f, s = 0.f;
    for (int k = t; k < 1024; k += 64) {
        a += psum[(size_t)c * 1024 + k];
        s += psum[(size_t)C_SZ * 1024 + (size_t)c * 1024 + k];
    }
#pragma unroll
    for (int off = 32; off > 0; off >>= 1) {
        a += __shfl_down(a, off);
        s += __shfl_down(s, off);
    }
    if (t == 0) {
        const float inv = 1.0f / (float)(B_SZ * N_SZ);
        float mean = a * inv;
        float var = s * inv - mean * mean;
        float rstd = rsqrtf(var + 1e-5f);
        float scale = rstd * gamma[c];
        mr[c] = scale;
        mr[256 + c] = beta[c] - mean * scale;
    }
}

// ---- kernel 3: v = relu(v*scale[c] + shift[c]), float4 ----
__global__ void bn_apply(float* __restrict__ out, const float* __restrict__ mr) {
    const int total4 = (B_SZ * C_SZ * N_SZ) / 4;
    f32x4* o4 = (f32x4*)out;
    for (int i = blockIdx.x * blockDim.x + threadIdx.x; i < total4;
         i += gridDim.x * blockDim.x) {
        f32x4 v = o4[i];
        int e0 = i * 4;
#pragma unroll
        for (int k = 0; k < 4; ++k) {
            int c = ((e0 + k) / N_SZ) & 255;
            float t = v[k] * mr[c] + mr[256 + c];
            v[k] = t > 0.f ? t : 0.f;
        }
        o4[i] = v;
    }
}

extern "C" void kernel_launch(void* const* d_in, const int* in_sizes, int n_in,
                              void* d_out, int out_size, void* d_ws, size_t ws_size,
                              hipStream_t stream) {
    const float* x     = (const float*)d_in[0];
    const float* adj   = (const float*)d_in[1];
    const float* w     = (const float*)d_in[2];
    const float* gamma = (const float*)d_in[3];
    const float* beta  = (const float*)d_in[4];
    float* out = (float*)d_out;

    // workspace: wt 1MB | psum 2MB | mr 2KB
    unsigned short* wt = (unsigned short*)d_ws;
    char* p = (char*)d_ws + (size_t)R_SZ * C_SZ * C_SZ * 2;
    float* psum = (float*)p;
    float* mr = (float*)(p + (size_t)2 * 1024 * C_SZ * 4);

    prep_wt<<<(R_SZ * C_SZ * C_SZ + 255) / 256, 256, 0, stream>>>(w, wt);
    rgcn_main<<<1024, TH, 0, stream>>>(x, adj, wt, out, psum);
    bn_stats<<<C_SZ, 64, 0, stream>>>(psum, gamma, beta, mr);
    bn_apply<<<2048, 256, 0, stream>>>(out, mr);
}

// Round 7
// 293.590 us; speedup vs baseline: 1.3643x; 1.3643x over previous
//
#include <hip/hip_runtime.h>

// RGCN block: B=512, C=256, R=8, N=81 (9x9), fp32 in/out, bf16 MFMA compute.
// Transposed formulation: msgT[c][n] = h^T @ adj^T ; out^T[d][n] = W^T @ msg.
// Grid: 1024 blocks = (b, n-half of 48 rows). 8 waves, each 32 d x 48 n output.
// R7 = R6 overlap structure (dbuf adj+msg, ONE barrier/relation, aged adj
// prefetch) + R5's named-register wt double-buffer (no pointer arrays -> no
// scratch spill).

#define B_SZ 512
#define C_SZ 256
#define R_SZ 8
#define N_SZ 81
#define TH 512

typedef short bf16x8 __attribute__((ext_vector_type(8)));
typedef float f32x4 __attribute__((ext_vector_type(4)));

__device__ __forceinline__ unsigned short f2bf(float f) {
    union { float f; unsigned u; } v; v.f = f;
    unsigned r = v.u + 0x7FFFu + ((v.u >> 16) & 1u);   // RNE
    return (unsigned short)(r >> 16);
}

// pack 4 f32 -> 4 bf16 in one u64, v[0] lowest address
__device__ __forceinline__ unsigned long long pack4bf(f32x4 v) {
    unsigned long long r;
    r  = (unsigned long long)f2bf(v[0]);
    r |= (unsigned long long)f2bf(v[1]) << 16;
    r |= (unsigned long long)f2bf(v[2]) << 32;
    r |= (unsigned long long)f2bf(v[3]) << 48;
    return r;
}

// LDS: adj buffers 2 x [48][88] bf16 ; msg buffers 2 x (48 rows x 512 B, swizzled)
#define ADJ_OFF  0                      // 2 * 8448 = 16896 B
#define MSG_OFF  16896                  // 2 * 24576 = 49152 B
#define SMEM_SZ  (16896 + 49152 + 32)   // 66080 B -> 2 blocks/CU

__device__ __forceinline__ int adj_base(int buf) { return ADJ_OFF + buf * 8448; }

__device__ __forceinline__ int msg_addr(int buf, int n, int cbyte) {
    int s = (n ^ (n >> 3)) & 7;
    return MSG_OFF + buf * 24576 + n * 512 + (cbyte ^ (s << 4));
}

// ---- kernel 0: weight (R,C,C) fp32 -> WT[r][d][c] bf16 ----
__global__ void prep_wt(const float* __restrict__ w, unsigned short* __restrict__ wt) {
    int i = blockIdx.x * blockDim.x + threadIdx.x;
    if (i >= R_SZ * C_SZ * C_SZ) return;
    int r = i >> 16;
    int d = (i >> 8) & 255;
    int c = i & 255;
    wt[i] = f2bf(w[(r * C_SZ + c) * C_SZ + d]);
}

// ---- kernel 1: fused RGCN, one block per (batch, n-half) ----
__launch_bounds__(TH, 4)
__global__ void rgcn_main(const float* __restrict__ x,
                          const float* __restrict__ adj,
                          const unsigned short* __restrict__ wt,
                          float* __restrict__ out,
                          float* __restrict__ psum) {
    __shared__ __align__(16) unsigned char smem[SMEM_SZ];

    // XCD co-location (1024 % 8 == 0 -> bijective)
    const int bid  = blockIdx.x;
    const int xcd  = bid & 7;
    const int slot = bid >> 3;            // 0..127
    const int b    = xcd * 64 + (slot >> 1);
    const int half = slot & 1;
    const int n0   = half * 48;
    const int nvalid = half ? 33 : 48;
    const int cnt  = nvalid * N_SZ;

    const int tid  = threadIdx.x;
    const int lane = tid & 63;
    const int wave = tid >> 6;            // 0..7
    const int lr   = lane & 15;
    const int lk   = lane >> 4;
    const int cb   = wave * 32;           // this wave's 32 c rows (stage1) / d rows (stage2)

    const float* xb   = x + (size_t)b * C_SZ * N_SZ;
    const float* adjb = adj + ((size_t)b * R_SZ * N_SZ + n0) * N_SZ;

    // ---- h fragments in registers, relation-invariant (m>=81 zeroed) ----
    bf16x8 hfr[3][2];
#pragma unroll
    for (int kk = 0; kk < 3; ++kk) {
#pragma unroll
        for (int jc = 0; jc < 2; ++jc) {
            int c = cb + jc * 16 + lr;
            const float* src = xb + c * N_SZ;
#pragma unroll
            for (int e = 0; e < 8; ++e) {
                int m = kk * 32 + lk * 8 + e;
                hfr[kk][jc][e] = (m < N_SZ) ? (short)f2bf(src[m]) : (short)0;
            }
        }
    }

    // ---- zero both adj buffers (pads m>=81, rows n>=nvalid stay zero) ----
    for (int i = tid; i < 16896 / 4; i += TH) ((unsigned*)smem)[i] = 0;

    // ---- adj(0): load + write buf0; then issue adj(1) prefetch ----
    float pf[8];
#pragma unroll
    for (int u = 0; u < 8; ++u) {
        int i2 = tid + u * TH;
        pf[u] = (i2 < cnt) ? adjb[i2] : 0.f;
    }
    __syncthreads();   // zero-init complete before value stores
    {
        unsigned short* a0 = (unsigned short*)(smem + adj_base(0));
#pragma unroll
        for (int u = 0; u < 8; ++u) {
            int i2 = tid + u * TH;
            if (i2 < cnt) {
                int n = i2 / N_SZ, m = i2 - n * N_SZ;
                a0[n * 88 + m] = f2bf(pf[u]);
            }
        }
    }
    // prefetch adj(1) (consumed at next iteration's write -> fully aged)
#pragma unroll
    for (int u = 0; u < 8; ++u) {
        int i2 = tid + u * TH;
        pf[u] = (i2 < cnt) ? adjb[1 * (N_SZ * N_SZ) + i2] : 0.f;
    }
    __syncthreads();   // adj(0) ready

    const f32x4 vzero = {0.f, 0.f, 0.f, 0.f};
    f32x4 acc[2][3];
#pragma unroll
    for (int jd = 0; jd < 2; ++jd)
#pragma unroll
        for (int jn = 0; jn < 3; ++jn) acc[jd][jn] = vzero;

#pragma unroll 1
    for (int r = 0; r < R_SZ; ++r) {
        const int cur = r & 1;
        const unsigned short* adjc = (const unsigned short*)(smem + adj_base(cur));
        const unsigned short* wr   = wt + r * (C_SZ * C_SZ);

        // ---- stage 1: msgT[c][n] ; A=h (regs), B=adj (LDS, current buffer) ----
        f32x4 macc[2][3];
#pragma unroll
        for (int jc = 0; jc < 2; ++jc)
#pragma unroll
            for (int jn = 0; jn < 3; ++jn) macc[jc][jn] = vzero;

#pragma unroll
        for (int kk = 0; kk < 3; ++kk) {
            bf16x8 bfr[3];
#pragma unroll
            for (int jn = 0; jn < 3; ++jn)
                bfr[jn] = *(const bf16x8*)&adjc[(jn * 16 + lr) * 88 + kk * 32 + lk * 8];
#pragma unroll
            for (int jc = 0; jc < 2; ++jc)
#pragma unroll
                for (int jn = 0; jn < 3; ++jn)
                    macc[jc][jn] = __builtin_amdgcn_mfma_f32_16x16x32_bf16(hfr[kk][jc], bfr[jn], macc[jc][jn], 0, 0, 0);
        }

        // ---- issue first wt batch (kk 0..1): latency hides under barrier ----
        bf16x8 wA[2][2], wB[2][2];   // [dk][jd] named only -> stays in VGPRs
#pragma unroll
        for (int dk = 0; dk < 2; ++dk)
#pragma unroll
            for (int jd = 0; jd < 2; ++jd)
                wA[dk][jd] = *(const bf16x8*)&wr[(cb + jd * 16 + lr) * 256 + dk * 32 + lk * 8];

        // ---- write msg -> msgbuf[cur] (no barrier: prev readers already synced) ----
#pragma unroll
        for (int jc = 0; jc < 2; ++jc) {
#pragma unroll
            for (int jn = 0; jn < 3; ++jn) {
                int n = jn * 16 + lr;
                int cbyte = (cb + jc * 16 + lk * 4) * 2;
                *(unsigned long long*)(smem + msg_addr(cur, n, cbyte)) = pack4bf(macc[jc][jn]);
            }
        }

        // ---- write aged adj(r+1) -> other buffer; then issue adj(r+2) ----
        if (r < R_SZ - 1) {
            unsigned short* an = (unsigned short*)(smem + adj_base(cur ^ 1));
#pragma unroll
            for (int u = 0; u < 8; ++u) {
                int i2 = tid + u * TH;
                if (i2 < cnt) {
                    int n = i2 / N_SZ, m = i2 - n * N_SZ;
                    an[n * 88 + m] = f2bf(pf[u]);
                }
            }
            if (r < R_SZ - 2) {
                const float* src = adjb + (r + 2) * (N_SZ * N_SZ);
#pragma unroll
                for (int u = 0; u < 8; ++u) {
                    int i2 = tid + u * TH;
                    pf[u] = (i2 < cnt) ? src[i2] : 0.f;
                }
            }
        }

        __syncthreads();   // the ONLY barrier: msg[cur] + adj[cur^1] ready

        // ---- stage 2: acc += W^T @ msg (K=256), wt double-buffered (named regs) ----
        auto do2 = [&](bf16x8 (&wc)[2][2], bf16x8 (&wn)[2][2], int kk0, bool load) {
            if (load) {
#pragma unroll
                for (int dk = 0; dk < 2; ++dk)
#pragma unroll
                    for (int jd = 0; jd < 2; ++jd)
                        wn[dk][jd] = *(const bf16x8*)&wr[(cb + jd * 16 + lr) * 256 + (kk0 + 2 + dk) * 32 + lk * 8];
            }
#pragma unroll
            for (int dk = 0; dk < 2; ++dk) {
                int kk = kk0 + dk;
                bf16x8 bfr[3];
#pragma unroll
                for (int jn = 0; jn < 3; ++jn)
                    bfr[jn] = *(const bf16x8*)(smem + msg_addr(cur, jn * 16 + lr, kk * 64 + lk * 16));
#pragma unroll
                for (int jd = 0; jd < 2; ++jd)
#pragma unroll
                    for (int jn = 0; jn < 3; ++jn)
                        acc[jd][jn] = __builtin_amdgcn_mfma_f32_16x16x32_bf16(wc[dk][jd], bfr[jn], acc[jd][jn], 0, 0, 0);
            }
        };
        do2(wA, wB, 0, true);
        do2(wB, wA, 2, true);
        do2(wA, wB, 4, true);
        do2(wB, wA, 6, false);
    }

    // ---- epilogue: pre = out^T + x ; n-contiguous stores ; BN partials ----
    float* outb = out + (size_t)b * C_SZ * N_SZ;
    const int bh = b * 2 + half;
#pragma unroll
    for (int jd = 0; jd < 2; ++jd) {
        float s1[4] = {0.f, 0.f, 0.f, 0.f};
        float s2[4] = {0.f, 0.f, 0.f, 0.f};
#pragma unroll
        for (int jn = 0; jn < 3; ++jn) {
            int nloc = jn * 16 + lr;
            bool ok = nloc < nvalid;
            int n = n0 + nloc;
#pragma unroll
            for (int q = 0; q < 4; ++q) {
                int d = cb + jd * 16 + lk * 4 + q;
                if (ok) {
                    float pre = acc[jd][jn][q] + xb[d * N_SZ + n];
                    outb[d * N_SZ + n] = pre;
                    s1[q] += pre;
                    s2[q] += pre * pre;
                }
            }
        }
#pragma unroll
        for (int q = 0; q < 4; ++q) {
#pragma unroll
            for (int msk = 8; msk > 0; msk >>= 1) {
                s1[q] += __shfl_xor(s1[q], msk);
                s2[q] += __shfl_xor(s2[q], msk);
            }
        }
        if (lr == 0) {
#pragma unroll
            for (int q = 0; q < 4; ++q) {
                int d = cb + jd * 16 + lk * 4 + q;
                psum[(size_t)d * 1024 + bh] = s1[q];
                psum[(size_t)C_SZ * 1024 + (size_t)d * 1024 + bh] = s2[q];
            }
        }
    }
}

// ---- kernel 2: reduce partials -> scale/shift per channel ----
__global__ void bn_stats(const float* __restrict__ psum,
                         const float* __restrict__ gamma, const float* __restrict__ beta,
                         float* __restrict__ mr) {
    int c = blockIdx.x;      // 256 blocks x 64 threads
    int t = threadIdx.x;
    float a = 0.f, s = 0.f;
    for (int k = t; k < 1024; k += 64) {
        a += psum[(size_t)c * 1024 + k];
        s += psum[(size_t)C_SZ * 1024 + (size_t)c * 1024 + k];
    }
#pragma unroll
    for (int off = 32; off > 0; off >>= 1) {
        a += __shfl_down(a, off);
        s += __shfl_down(s, off);
    }
    if (t == 0) {
        const float inv = 1.0f / (float)(B_SZ * N_SZ);
        float mean = a * inv;
        float var = s * inv - mean * mean;
        float rstd = rsqrtf(var + 1e-5f);
        float scale = rstd * gamma[c];
        mr[c] = scale;
        mr[256 + c] = beta[c] - mean * scale;
    }
}

// ---- kernel 3: v = relu(v*scale[c] + shift[c]), float4 ----
__global__ void bn_apply(float* __restrict__ out, const float* __restrict__ mr) {
    const int total4 = (B_SZ * C_SZ * N_SZ) / 4;
    f32x4* o4 = (f32x4*)out;
    for (int i = blockIdx.x * blockDim.x + threadIdx.x; i < total4;
         i += gridDim.x * blockDim.x) {
        f32x4 v = o4[i];
        int e0 = i * 4;
#pragma unroll
        for (int k = 0; k < 4; ++k) {
            int c = ((e0 + k) / N_SZ) & 255;
            float t = v[k] * mr[c] + mr[256 + c];
            v[k] = t > 0.f ? t : 0.f;
        }
        o4[i] = v;
    }
}

extern "C" void kernel_launch(void* const* d_in, const int* in_sizes, int n_in,
                              void* d_out, int out_size, void* d_ws, size_t ws_size,
                              hipStream_t stream) {
    const float* x     = (const float*)d_in[0];
    const float* adj   = (const float*)d_in[1];
    const float* w     = (const float*)d_in[2];
    const float* gamma = (const float*)d_in[3];
    const float* beta  = (const float*)d_in[4];
    float* out = (float*)d_out;

    // workspace: wt 1MB | psum 2MB | mr 2KB
    unsigned short* wt = (unsigned short*)d_ws;
    char* p = (char*)d_ws + (size_t)R_SZ * C_SZ * C_SZ * 2;
    float* psum = (float*)p;
    float* mr = (float*)(p + (size_t)2 * 1024 * C_SZ * 4);

    prep_wt<<<(R_SZ * C_SZ * C_SZ + 255) / 256, 256, 0, stream>>>(w, wt);
    rgcn_main<<<1024, TH, 0, stream>>>(x, adj, wt, out, psum);
    bn_stats<<<C_SZ, 64, 0, stream>>>(psum, gamma, beta, mr);
    bn_apply<<<2048, 256, 0, stream>>>(out, mr);
}